// Round 10
// baseline (5085.418 us; speedup 1.0000x reference)
//
#include <hip/hip_runtime.h>

// Decoder: B=256, T=128, ENC=256, DEC=256, OUT=3. All fp32 in/out.
//
// Round 10: r8 base (proven 1884 us) + whh-stream fusion into phases S and C.
// r9 lesson (banked): lane-adjacent remaps of hcv/z2s reads -> 1.68e8 bank
// conflicts (was 262K). Keep r8's wave-uniform secondary indices (broadcasts
// are free). This round changes NO LDS access pattern:
//  - gates_h = whh.h feeds only Phase G, not S/C -> its 512 KB stream (the
//    largest) is interleaved into the S and C loop bodies (16 kc in each),
//    consume-as-arrive (<=2 chunk-pairs live), accumulators g0,g1 carry
//    across B3/B4 like the proven ghr pattern. whh BW hides under S/C VALU.
//  - Phase Z becomes a1-only.
// No-deep-unroll rule stands (r4-r7: 6.3 GB/dispatch scratch spills).
// Predicted: ~12.1-13.1 us/step -> 1.55-1.68 ms; WRITE_SIZE ~384 KB;
// conflicts ~262K; VALUBusy 45-50%.

#define TT 128
#define SCL 2.885390081777927f  // 2*log2(e)

typedef _Float16 h2v __attribute__((ext_vector_type(2)));
typedef _Float16 f16x4 __attribute__((ext_vector_type(4)));
typedef _Float16 f16x8 __attribute__((ext_vector_type(8)));

__device__ __forceinline__ float fdot2(h2v a, h2v b, float c) {
#if __has_builtin(__builtin_amdgcn_fdot2)
  return __builtin_amdgcn_fdot2(a, b, c, false);
#else
  return c + (float)a[0] * (float)b[0] + (float)a[1] * (float)b[1];
#endif
}

__device__ __forceinline__ float exp2_fast(float x) {
#if __has_builtin(__builtin_amdgcn_exp2f)
  return __builtin_amdgcn_exp2f(x);
#else
  return exp2f(x);
#endif
}
__device__ __forceinline__ float rcp_fast(float x) {
#if __has_builtin(__builtin_amdgcn_rcpf)
  return __builtin_amdgcn_rcpf(x);
#else
  return 1.f / x;
#endif
}

__device__ __forceinline__ float tanh_scaled(float s) {  // s = SCL*v
  return fmaf(-2.f, rcp_fast(exp2_fast(s) + 1.f), 1.f);
}
__device__ __forceinline__ float fast_sig(float x) {
  return rcp_fast(1.f + __expf(-x));
}
__device__ __forceinline__ float fast_tanh(float x) {
  return tanh_scaled(x * SCL);
}

__device__ __forceinline__ float dot8(f16x8 w, f16x8 h, float acc) {
  h2v w0 = __builtin_shufflevector(w, w, 0, 1), h0 = __builtin_shufflevector(h, h, 0, 1);
  h2v w1 = __builtin_shufflevector(w, w, 2, 3), h1 = __builtin_shufflevector(h, h, 2, 3);
  h2v w2 = __builtin_shufflevector(w, w, 4, 5), h2 = __builtin_shufflevector(h, h, 4, 5);
  h2v w3 = __builtin_shufflevector(w, w, 6, 7), h3 = __builtin_shufflevector(h, h, 6, 7);
  acc = fdot2(w0, h0, acc);
  acc = fdot2(w1, h1, acc);
  acc = fdot2(w2, h2, acc);
  acc = fdot2(w3, h3, acc);
  return acc;
}

// ---------------- precompute kernels ----------------

__global__ void k_transpose(const float* __restrict__ src, float* __restrict__ dst,
                            int R, int C) {
  int idx = blockIdx.x * 256 + threadIdx.x;
  if (idx >= R * C) return;
  int r = idx / C, c = idx - r * C;
  dst[(size_t)c * R + r] = src[idx];
}

// z2h[row][f] = SCL*(sum_e x[row][e]*attn2_w[f][e] + a2b[f] + a1b[f]) fp16
// + emits xTg[b][e][t] fp16 via 2x f16x8 vector stores per thread.
__global__ __launch_bounds__(256) void k_z2x(const float* __restrict__ x,
                                             const float* __restrict__ a2wT,
                                             const float* __restrict__ a2b,
                                             const float* __restrict__ a1b,
                                             _Float16* __restrict__ z2h,
                                             _Float16* __restrict__ xTg) {
  __shared__ float xt[16][257];
  const int r0 = blockIdx.x * 16;
  const int tid = threadIdx.x;
  for (int idx = tid; idx < 16 * 256; idx += 256) {
    int rr = idx >> 8, e = idx & 255;
    xt[rr][e] = x[(size_t)(r0 + rr) * 256 + e];
  }
  __syncthreads();
  const int f = tid;
  float bias = a2b[f] + a1b[f];
  float acc[16];
#pragma unroll
  for (int rr = 0; rr < 16; ++rr) acc[rr] = bias;
  for (int e = 0; e < 256; ++e) {
    float w = a2wT[(size_t)e * 256 + f];
#pragma unroll
    for (int rr = 0; rr < 16; ++rr) acc[rr] += w * xt[rr][e];
  }
#pragma unroll
  for (int rr = 0; rr < 16; ++rr)
    z2h[(size_t)(r0 + rr) * 256 + f] = (_Float16)(acc[rr] * SCL);
  const int bb = r0 >> 7, t0 = r0 & 127;
  f16x8 lo, hi;
#pragma unroll
  for (int rr = 0; rr < 8; ++rr) lo[rr] = (_Float16)xt[rr][f];
#pragma unroll
  for (int rr = 0; rr < 8; ++rr) hi[rr] = (_Float16)xt[8 + rr][f];
  _Float16* d = &xTg[((size_t)bb * 256 + f) * 128 + t0];
  *(f16x8*)d = lo;
  *(f16x8*)(d + 8) = hi;
}

// a1p8[kc][f][8] = attn1_w[f][kc*8+j] * SCL   (kc<64, f<256)
__global__ void k_pack_a1(const float* __restrict__ a1w, _Float16* __restrict__ dst) {
  int idx = blockIdx.x * 256 + threadIdx.x;  // 131072
  int j = idx & 7, f = (idx >> 3) & 255, kc = idx >> 11;
  dst[idx] = (_Float16)(a1w[(size_t)f * 512 + kc * 8 + j] * SCL);
}

// whh8[kc][n][8] = w_hh[n][kc*8+j]   (kc<32, n<1024)
__global__ void k_pack_whh(const float* __restrict__ whh, _Float16* __restrict__ dst) {
  int idx = blockIdx.x * 256 + threadIdx.x;  // 262144
  int j = idx & 7, n = (idx >> 3) & 1023, kc = idx >> 13;
  dst[idx] = (_Float16)whh[(size_t)n * 256 + kc * 8 + j];
}

// wc8[kc][n][8] fp16 of (w_ih @ tilde_w)[n][kc*8+j], k>=259 zero-padded (kc<33)
__global__ __launch_bounds__(320) void k_wcomb(const float* __restrict__ w_ih,
                                               const float* __restrict__ tilde_w,
                                               const float* __restrict__ tilde_b,
                                               const float* __restrict__ b_ih,
                                               const float* __restrict__ b_hh,
                                               _Float16* __restrict__ wc8,
                                               float* __restrict__ bcomb) {
  __shared__ float wrow[512];
  __shared__ float bred[320];
  const int n = blockIdx.x;
  const int tid = threadIdx.x;
  for (int j = tid; j < 512; j += 320) wrow[j] = w_ih[(size_t)n * 512 + j];
  __syncthreads();
  if (tid < 264) {
    float acc = 0.f;
    if (tid < 259)
      for (int j = 0; j < 512; ++j) acc += wrow[j] * tilde_w[(size_t)j * 259 + tid];
    wc8[(size_t)(tid >> 3) * 8192 + n * 8 + (tid & 7)] = (_Float16)acc;
  }
  float p = 0.f;
  for (int j = tid; j < 512; j += 320) p += wrow[j] * tilde_b[j];
  bred[tid] = p;
  __syncthreads();
  if (tid == 0) {
    float s = 0.f;
    for (int j = 0; j < 320; ++j) s += bred[j];
    bcomb[n] = s + b_ih[n] + b_hh[n];
  }
}

// whead[o][k] = fc2_w @ fc1_w; bhead[o] = fc2_w[o]·fc1_b + fc2_b[o]
__global__ __launch_bounds__(512) void k_whead(const float* __restrict__ fc1_w,
                                               const float* __restrict__ fc1_b,
                                               const float* __restrict__ fc2_w,
                                               const float* __restrict__ fc2_b,
                                               float* __restrict__ whead,
                                               float* __restrict__ bhead) {
  const int k = threadIdx.x;
#pragma unroll
  for (int o = 0; o < 3; ++o) {
    float acc = 0.f;
    for (int j = 0; j < 256; ++j) acc += fc2_w[o * 256 + j] * fc1_w[(size_t)j * 512 + k];
    whead[o * 512 + k] = acc;
  }
  if (k < 3) {
    float acc = fc2_b[k];
    for (int j = 0; j < 256; ++j) acc += fc2_w[k * 256 + j] * fc1_b[j];
    bhead[k] = acc;
  }
}

// ---------------- main persistent decoder ----------------

__global__ __launch_bounds__(1024, 4) void k_decoder(
    const _Float16* __restrict__ z2g,  // [32768][256] fp16, pre-scaled, incl biases
    const _Float16* __restrict__ xTg,  // [256][256 e][128 t] fp16
    const float* __restrict__ yg,      // y_seq [256][128][3] fp32
    const float* __restrict__ a3w,     // [256]
    const _Float16* __restrict__ a1p8, // [64 kc][256 f][8]
    const _Float16* __restrict__ whh8, // [32 kc][1024 n][8]
    const _Float16* __restrict__ wc8,  // [33 kc][1024 n][8]
    const float* __restrict__ bcomb,   // [1024]
    const float* __restrict__ whead,   // [3][512]
    const float* __restrict__ bhead,   // [3]
    float* __restrict__ outg)          // [256][128][3]
{
  __shared__ __align__(16) _Float16 z2s[128][260];  // 66,560 B
  __shared__ __align__(16) _Float16 xs[256][132];   // 67,584 B
  __shared__ float zpart[1024];
  __shared__ float scpart[1024];
  __shared__ float cpart[1024];
  __shared__ float gbuf[1024];
  __shared__ float z1c[256];
  __shared__ float hbuf[256], cbuf[256], ctxs[256], w3s[256];
  __shared__ __align__(16) _Float16 hc8[512];  // [h(256); c(256)]
  __shared__ __align__(16) _Float16 u8[264];   // [y(3); ctx(256); pad0(5)]
  __shared__ float attv[128];
  __shared__ float sred[8];

  const int b = blockIdx.x;
  const int tid = threadIdx.x;

  // stage z2[b] -> [t][260], xT[b] -> [e][132]
  {
    const f16x8* zsrc = (const f16x8*)(z2g + (size_t)b * TT * 256);
    for (int c = tid; c < 4096; c += 1024) {
      int t = c >> 5, fc = c & 31;
      f16x8 v = zsrc[c];
      f16x4 lo = __builtin_shufflevector(v, v, 0, 1, 2, 3);
      f16x4 hi = __builtin_shufflevector(v, v, 4, 5, 6, 7);
      _Float16* d = &z2s[t][fc * 8];
      *(f16x4*)d = lo;
      *(f16x4*)(d + 4) = hi;
    }
    const f16x8* xsrc = (const f16x8*)(xTg + (size_t)b * 256 * 128);
    for (int c = tid; c < 4096; c += 1024) {
      int e = c >> 4, tc = c & 15;
      f16x8 v = xsrc[c];
      f16x4 lo = __builtin_shufflevector(v, v, 0, 1, 2, 3);
      f16x4 hi = __builtin_shufflevector(v, v, 4, 5, 6, 7);
      _Float16* d = &xs[e][tc * 8];
      *(f16x4*)d = lo;
      *(f16x4*)(d + 4) = hi;
    }
  }
  if (tid < 256) {
    w3s[tid] = a3w[tid];
    hbuf[tid] = 0.f; cbuf[tid] = 0.f;
    hc8[tid] = (_Float16)0.f; hc8[256 + tid] = (_Float16)0.f;
  }
  if (tid >= 259 && tid < 264) u8[tid] = (_Float16)0.f;
  __syncthreads();  // B0

  const int f_z = tid & 255;
  const int qz = tid >> 8;  // k-quarter for z1 (wave-uniform)
  const _Float16* pa = a1p8 + ((size_t)(qz * 16) * 256 + f_z) * 8;
  const _Float16* pw = whh8 + (size_t)tid * 8;
  const _Float16* pc = wc8 + (size_t)tid * 8;
  const f16x8* hcv = (const f16x8*)hc8;
  const float bc = bcomb[tid];

  // head weights resident in registers
  float whr[8], bh = 0.f;
  if (tid < 192) {
    int o = tid >> 6, lane = tid & 63;
#pragma unroll
    for (int q2 = 0; q2 < 8; ++q2) whr[q2] = whead[o * 512 + lane + (q2 << 6)];
    bh = bhead[o];
  }

  for (int t = 0; t < TT; ++t) {
    float yreg = (tid < 3) ? yg[(size_t)(b * TT + t) * 3 + tid] : 0.f;

    // ---- Phase Z: z1 partials only (a1 stream; whh moved into S/C).
    // Compact unroll-4 loops only (r4-r7 deep unrolls spilled 6.3 GB — keep).
    {
      float za0 = 0.f, za1 = 0.f;
#pragma unroll 4
      for (int i = 0; i < 16; i += 2) {
        f16x8 w0 = *(const f16x8*)(pa + (size_t)i * 2048);
        f16x8 w1 = *(const f16x8*)(pa + (size_t)(i + 1) * 2048);
        f16x8 h0 = hcv[qz * 16 + i];
        f16x8 h1 = hcv[qz * 16 + i + 1];
        za0 = dot8(w0, h0, za0);
        za1 = dot8(w1, h1, za1);
      }
      zpart[tid] = za0 + za1;
    }
    __syncthreads();  // B1

    if (tid < 256)
      z1c[tid] = zpart[tid] + zpart[tid + 256] + zpart[tid + 512] + zpart[tid + 768];
    __syncthreads();  // B2

    // whh accumulators: live across B3/B4 (2 f32 regs, like the proven ghr)
    float g0 = 0.f, g1 = 0.f;

    // ---- Phase S + whh[0..16): tp = tid&127, q = tid>>7 (wave-uniform q)
    {
      int tp = tid & 127, q = tid >> 7, f0 = q * 32;
      const _Float16* zr = &z2s[tp][f0];
      float acc = 0.f;
#pragma unroll
      for (int i = 0; i < 8; ++i) {
        // whh kc-pair 2i, 2i+1 (loads hide under the tanh VALU below)
        {
          int kc = 2 * i;
          f16x8 w0 = *(const f16x8*)(pw + (size_t)kc * 8192);
          f16x8 w1 = *(const f16x8*)(pw + (size_t)(kc + 1) * 8192);
          g0 = dot8(w0, hcv[kc], g0);
          g1 = dot8(w1, hcv[kc + 1], g1);
        }
        f16x4 zz = *(const f16x4*)(zr + i * 4);
#pragma unroll
        for (int j = 0; j < 4; ++j) {
          int f = f0 + i * 4 + j;
          acc = fmaf(tanh_scaled(z1c[f] + (float)zz[j]), w3s[f], acc);
        }
      }
      scpart[tid] = acc;
    }
    __syncthreads();  // B3

    // ---- softmax (no max-sub: |score| <= sum|w3| ~ 25 << 88)
    if (tid < 128) {
      float sc = scpart[tid] + scpart[tid + 128] + scpart[tid + 256] + scpart[tid + 384] +
                 scpart[tid + 512] + scpart[tid + 640] + scpart[tid + 768] + scpart[tid + 896];
      float e = __expf(sc);
      attv[tid] = e;
      float s = e;
#pragma unroll
      for (int off = 32; off > 0; off >>= 1) s += __shfl_xor(s, off);
      if ((tid & 63) == 0) sred[2 + (tid >> 6)] = s;
    }
    __syncthreads();  // B4

    // ---- Phase C + whh[16..32): e = tid&255, th4 = tid>>8 (wave-uniform)
    {
      int e = tid & 255, th4 = tid >> 8;
      const _Float16* xr = &xs[e][th4 * 32];
      float acc = 0.f;
#pragma unroll
      for (int i = 0; i < 8; ++i) {
        // whh kc-pair 16+2i, 17+2i
        {
          int kc = 16 + 2 * i;
          f16x8 w0 = *(const f16x8*)(pw + (size_t)kc * 8192);
          f16x8 w1 = *(const f16x8*)(pw + (size_t)(kc + 1) * 8192);
          g0 = dot8(w0, hcv[kc], g0);
          g1 = dot8(w1, hcv[kc + 1], g1);
        }
        f16x4 xv = *(const f16x4*)(xr + i * 4);
#pragma unroll
        for (int j = 0; j < 4; ++j)
          acc = fmaf(attv[th4 * 32 + i * 4 + j], (float)xv[j], acc);
      }
      cpart[tid] = acc;
    }
    const float ghr = g0 + g1;
    __syncthreads();  // B5

    const float rsum = rcp_fast(sred[2] + sred[3]);
    if (tid < 256) {
      float cv = (cpart[tid] + cpart[tid + 256] + cpart[tid + 512] + cpart[tid + 768]) * rsum;
      ctxs[tid] = cv;
      u8[3 + tid] = (_Float16)cv;
    }
    if (tid < 3) u8[tid] = (_Float16)yreg;
    __syncthreads();  // B6

    // ---- Phase G: gates = W_comb·u + gates_h + b_comb (n = tid)
    {
      float a0 = 0.f, a1 = 0.f;
#pragma unroll 4
      for (int kc = 0; kc < 32; kc += 2) {
        f16x8 w0 = *(const f16x8*)(pc + (size_t)kc * 8192);
        f16x8 w1 = *(const f16x8*)(pc + (size_t)(kc + 1) * 8192);
        f16x8 u0 = *(const f16x8*)&u8[kc * 8];
        f16x8 u1 = *(const f16x8*)&u8[(kc + 1) * 8];
        a0 = dot8(w0, u0, a0);
        a1 = dot8(w1, u1, a1);
      }
      a0 = dot8(*(const f16x8*)(pc + (size_t)32 * 8192), *(const f16x8*)&u8[256], a0);
      gbuf[tid] = a0 + a1 + ghr + bc;
    }
    __syncthreads();  // B7

    // ---- LSTM pointwise
    if (tid < 256) {
      float gi = gbuf[tid], gf = gbuf[tid + 256], gg = gbuf[tid + 512], go = gbuf[tid + 768];
      float cn = fast_sig(gf) * cbuf[tid] + fast_sig(gi) * fast_tanh(gg);
      float hn = fast_sig(go) * fast_tanh(cn);
      if (t < TT - 1) {  // reference skips state update on last step
        hbuf[tid] = hn; cbuf[tid] = cn;
        hc8[tid] = (_Float16)hn; hc8[256 + tid] = (_Float16)cn;
      }
    }
    __syncthreads();  // B8

    // ---- Phase H: out[b,t,o] = W_head[o]·[h2, ctx] + b_head[o]
    if (tid < 192) {
      int o = tid >> 6, lane = tid & 63;
      float acc = 0.f;
#pragma unroll
      for (int q2 = 0; q2 < 8; ++q2) {
        int k = lane + (q2 << 6);
        float v = (k < 256) ? hbuf[k] : ctxs[k - 256];
        acc = fmaf(whr[q2], v, acc);
      }
#pragma unroll
      for (int off = 32; off > 0; off >>= 1) acc += __shfl_xor(acc, off);
      if (lane == 0) outg[(size_t)(b * TT + t) * 3 + o] = acc + bh;
    }
    // no barrier: next phase writes only zpart (disjoint from hbuf/ctxs)
  }
}

// ---------------- launch ----------------

extern "C" void kernel_launch(void* const* d_in, const int* in_sizes, int n_in,
                              void* d_out, int out_size, void* d_ws, size_t ws_size,
                              hipStream_t stream) {
  const float* x   = (const float*)d_in[0];
  const float* y   = (const float*)d_in[1];
  const float* a1w = (const float*)d_in[2];
  const float* a1b = (const float*)d_in[3];
  const float* a2w = (const float*)d_in[4];
  const float* a2b = (const float*)d_in[5];
  const float* a3w = (const float*)d_in[6];
  // d_in[7] = attn3_b: softmax-invariant constant, skipped
  const float* tw  = (const float*)d_in[8];
  const float* tb  = (const float*)d_in[9];
  const float* wih = (const float*)d_in[10];
  const float* whh = (const float*)d_in[11];
  const float* bih = (const float*)d_in[12];
  const float* bhh = (const float*)d_in[13];
  const float* f1w = (const float*)d_in[14];
  const float* f1b = (const float*)d_in[15];
  const float* f2w = (const float*)d_in[16];
  const float* f2b = (const float*)d_in[17];
  float* out = (float*)d_out;

  float* ws = (float*)d_ws;
  _Float16* z2h  = (_Float16*)ws;                       // 8,388,608 h = 4,194,304 f
  _Float16* xT   = (_Float16*)(ws + 4194304);           // 8,388,608 h
  float* a2wT    = ws + 8388608;                        // 65,536 f
  _Float16* a1p8 = (_Float16*)(ws + 8388608 + 65536);   // 131,072 h
  _Float16* whh8 = (_Float16*)(ws + 8388608 + 131072);  // 262,144 h
  _Float16* wc8  = (_Float16*)(ws + 8388608 + 262144);  // 270,336 h
  float* bcomb   = ws + 8388608 + 262144 + 135168;      // 1,024
  float* whead   = bcomb + 1024;                        // 1,536
  float* bhead   = whead + 1536;                        // 3

  k_transpose<<<dim3((256 * 256 + 255) / 256), dim3(256), 0, stream>>>(a2w, a2wT, 256, 256);
  k_z2x<<<dim3(2048), dim3(256), 0, stream>>>(x, a2wT, a2b, a1b, z2h, xT);
  k_pack_a1<<<dim3(512), dim3(256), 0, stream>>>(a1w, a1p8);
  k_pack_whh<<<dim3(1024), dim3(256), 0, stream>>>(whh, whh8);
  k_wcomb<<<dim3(1024), dim3(320), 0, stream>>>(wih, tw, tb, bih, bhh, wc8, bcomb);
  k_whead<<<dim3(1), dim3(512), 0, stream>>>(f1w, f1b, f2w, f2b, whead, bhead);

  k_decoder<<<dim3(256), dim3(1024), 0, stream>>>(z2h, xT, y, a3w, a1p8, whh8, wc8,
                                                  bcomb, whead, bhead, out);
}

// Round 11
// 1889.761 us; speedup vs baseline: 2.6910x; 2.6910x over previous
//
#include <hip/hip_runtime.h>

// Decoder: B=256, T=128, ENC=256, DEC=256, OUT=3. All fp32 in/out.
//
// Round 11: r8 byte-exact (proven 1884 us) with ONE variable changed:
// #pragma unroll 4 -> 8 on the two 512KB stream loops (whh in Z, wc in G),
// testing whether the measured 88 GB/s/CU stream rate is issue-clustering
// (unroll-4 shows 8 independent loads) or a true pattern ceiling.
// Failure catalog (all banked, do not retry):
//  r4-r7: manual deep unroll/prefetch -> 6.3 GB scratch spill (VGPR pinned 64).
//  r9: lane-adjacent LDS remaps -> 1.68e8 bank conflicts (keep wave-uniform
//      secondary indices; broadcasts are free).
//  r10: weight stream interleaved into S/C VALU loops -> L2 miss explosion
//      (FETCH 22MB -> 11.25GB); sweeps must stay burst-contiguous per phase.
// Tripwires: WRITE_SIZE ~384KB, conflicts ~262K, FETCH ~21.9MB.

#define TT 128
#define SCL 2.885390081777927f  // 2*log2(e)

typedef _Float16 h2v __attribute__((ext_vector_type(2)));
typedef _Float16 f16x4 __attribute__((ext_vector_type(4)));
typedef _Float16 f16x8 __attribute__((ext_vector_type(8)));

__device__ __forceinline__ float fdot2(h2v a, h2v b, float c) {
#if __has_builtin(__builtin_amdgcn_fdot2)
  return __builtin_amdgcn_fdot2(a, b, c, false);
#else
  return c + (float)a[0] * (float)b[0] + (float)a[1] * (float)b[1];
#endif
}

__device__ __forceinline__ float exp2_fast(float x) {
#if __has_builtin(__builtin_amdgcn_exp2f)
  return __builtin_amdgcn_exp2f(x);
#else
  return exp2f(x);
#endif
}
__device__ __forceinline__ float rcp_fast(float x) {
#if __has_builtin(__builtin_amdgcn_rcpf)
  return __builtin_amdgcn_rcpf(x);
#else
  return 1.f / x;
#endif
}

__device__ __forceinline__ float tanh_scaled(float s) {  // s = SCL*v
  return fmaf(-2.f, rcp_fast(exp2_fast(s) + 1.f), 1.f);
}
__device__ __forceinline__ float fast_sig(float x) {
  return rcp_fast(1.f + __expf(-x));
}
__device__ __forceinline__ float fast_tanh(float x) {
  return tanh_scaled(x * SCL);
}

__device__ __forceinline__ float dot8(f16x8 w, f16x8 h, float acc) {
  h2v w0 = __builtin_shufflevector(w, w, 0, 1), h0 = __builtin_shufflevector(h, h, 0, 1);
  h2v w1 = __builtin_shufflevector(w, w, 2, 3), h1 = __builtin_shufflevector(h, h, 2, 3);
  h2v w2 = __builtin_shufflevector(w, w, 4, 5), h2 = __builtin_shufflevector(h, h, 4, 5);
  h2v w3 = __builtin_shufflevector(w, w, 6, 7), h3 = __builtin_shufflevector(h, h, 6, 7);
  acc = fdot2(w0, h0, acc);
  acc = fdot2(w1, h1, acc);
  acc = fdot2(w2, h2, acc);
  acc = fdot2(w3, h3, acc);
  return acc;
}

// ---------------- precompute kernels ----------------

__global__ void k_transpose(const float* __restrict__ src, float* __restrict__ dst,
                            int R, int C) {
  int idx = blockIdx.x * 256 + threadIdx.x;
  if (idx >= R * C) return;
  int r = idx / C, c = idx - r * C;
  dst[(size_t)c * R + r] = src[idx];
}

// z2h[row][f] = SCL*(sum_e x[row][e]*attn2_w[f][e] + a2b[f] + a1b[f]) fp16
// + emits xTg[b][e][t] fp16 via 2x f16x8 vector stores per thread.
__global__ __launch_bounds__(256) void k_z2x(const float* __restrict__ x,
                                             const float* __restrict__ a2wT,
                                             const float* __restrict__ a2b,
                                             const float* __restrict__ a1b,
                                             _Float16* __restrict__ z2h,
                                             _Float16* __restrict__ xTg) {
  __shared__ float xt[16][257];
  const int r0 = blockIdx.x * 16;
  const int tid = threadIdx.x;
  for (int idx = tid; idx < 16 * 256; idx += 256) {
    int rr = idx >> 8, e = idx & 255;
    xt[rr][e] = x[(size_t)(r0 + rr) * 256 + e];
  }
  __syncthreads();
  const int f = tid;
  float bias = a2b[f] + a1b[f];
  float acc[16];
#pragma unroll
  for (int rr = 0; rr < 16; ++rr) acc[rr] = bias;
  for (int e = 0; e < 256; ++e) {
    float w = a2wT[(size_t)e * 256 + f];
#pragma unroll
    for (int rr = 0; rr < 16; ++rr) acc[rr] += w * xt[rr][e];
  }
#pragma unroll
  for (int rr = 0; rr < 16; ++rr)
    z2h[(size_t)(r0 + rr) * 256 + f] = (_Float16)(acc[rr] * SCL);
  const int bb = r0 >> 7, t0 = r0 & 127;
  f16x8 lo, hi;
#pragma unroll
  for (int rr = 0; rr < 8; ++rr) lo[rr] = (_Float16)xt[rr][f];
#pragma unroll
  for (int rr = 0; rr < 8; ++rr) hi[rr] = (_Float16)xt[8 + rr][f];
  _Float16* d = &xTg[((size_t)bb * 256 + f) * 128 + t0];
  *(f16x8*)d = lo;
  *(f16x8*)(d + 8) = hi;
}

// a1p8[kc][f][8] = attn1_w[f][kc*8+j] * SCL   (kc<64, f<256)
__global__ void k_pack_a1(const float* __restrict__ a1w, _Float16* __restrict__ dst) {
  int idx = blockIdx.x * 256 + threadIdx.x;  // 131072
  int j = idx & 7, f = (idx >> 3) & 255, kc = idx >> 11;
  dst[idx] = (_Float16)(a1w[(size_t)f * 512 + kc * 8 + j] * SCL);
}

// whh8[kc][n][8] = w_hh[n][kc*8+j]   (kc<32, n<1024)
__global__ void k_pack_whh(const float* __restrict__ whh, _Float16* __restrict__ dst) {
  int idx = blockIdx.x * 256 + threadIdx.x;  // 262144
  int j = idx & 7, n = (idx >> 3) & 1023, kc = idx >> 13;
  dst[idx] = (_Float16)whh[(size_t)n * 256 + kc * 8 + j];
}

// wc8[kc][n][8] fp16 of (w_ih @ tilde_w)[n][kc*8+j], k>=259 zero-padded (kc<33)
__global__ __launch_bounds__(320) void k_wcomb(const float* __restrict__ w_ih,
                                               const float* __restrict__ tilde_w,
                                               const float* __restrict__ tilde_b,
                                               const float* __restrict__ b_ih,
                                               const float* __restrict__ b_hh,
                                               _Float16* __restrict__ wc8,
                                               float* __restrict__ bcomb) {
  __shared__ float wrow[512];
  __shared__ float bred[320];
  const int n = blockIdx.x;
  const int tid = threadIdx.x;
  for (int j = tid; j < 512; j += 320) wrow[j] = w_ih[(size_t)n * 512 + j];
  __syncthreads();
  if (tid < 264) {
    float acc = 0.f;
    if (tid < 259)
      for (int j = 0; j < 512; ++j) acc += wrow[j] * tilde_w[(size_t)j * 259 + tid];
    wc8[(size_t)(tid >> 3) * 8192 + n * 8 + (tid & 7)] = (_Float16)acc;
  }
  float p = 0.f;
  for (int j = tid; j < 512; j += 320) p += wrow[j] * tilde_b[j];
  bred[tid] = p;
  __syncthreads();
  if (tid == 0) {
    float s = 0.f;
    for (int j = 0; j < 320; ++j) s += bred[j];
    bcomb[n] = s + b_ih[n] + b_hh[n];
  }
}

// whead[o][k] = fc2_w @ fc1_w; bhead[o] = fc2_w[o]·fc1_b + fc2_b[o]
__global__ __launch_bounds__(512) void k_whead(const float* __restrict__ fc1_w,
                                               const float* __restrict__ fc1_b,
                                               const float* __restrict__ fc2_w,
                                               const float* __restrict__ fc2_b,
                                               float* __restrict__ whead,
                                               float* __restrict__ bhead) {
  const int k = threadIdx.x;
#pragma unroll
  for (int o = 0; o < 3; ++o) {
    float acc = 0.f;
    for (int j = 0; j < 256; ++j) acc += fc2_w[o * 256 + j] * fc1_w[(size_t)j * 512 + k];
    whead[o * 512 + k] = acc;
  }
  if (k < 3) {
    float acc = fc2_b[k];
    for (int j = 0; j < 256; ++j) acc += fc2_w[k * 256 + j] * fc1_b[j];
    bhead[k] = acc;
  }
}

// ---------------- main persistent decoder ----------------

__global__ __launch_bounds__(1024, 4) void k_decoder(
    const _Float16* __restrict__ z2g,  // [32768][256] fp16, pre-scaled, incl biases
    const _Float16* __restrict__ xTg,  // [256][256 e][128 t] fp16
    const float* __restrict__ yg,      // y_seq [256][128][3] fp32
    const float* __restrict__ a3w,     // [256]
    const _Float16* __restrict__ a1p8, // [64 kc][256 f][8]
    const _Float16* __restrict__ whh8, // [32 kc][1024 n][8]
    const _Float16* __restrict__ wc8,  // [33 kc][1024 n][8]
    const float* __restrict__ bcomb,   // [1024]
    const float* __restrict__ whead,   // [3][512]
    const float* __restrict__ bhead,   // [3]
    float* __restrict__ outg)          // [256][128][3]
{
  __shared__ __align__(16) _Float16 z2s[128][260];  // 66,560 B
  __shared__ __align__(16) _Float16 xs[256][132];   // 67,584 B
  __shared__ float zpart[1024];
  __shared__ float scpart[1024];
  __shared__ float cpart[1024];
  __shared__ float gbuf[1024];
  __shared__ float z1c[256];
  __shared__ float hbuf[256], cbuf[256], ctxs[256], w3s[256];
  __shared__ __align__(16) _Float16 hc8[512];  // [h(256); c(256)]
  __shared__ __align__(16) _Float16 u8[264];   // [y(3); ctx(256); pad0(5)]
  __shared__ float attv[128];
  __shared__ float sred[8];

  const int b = blockIdx.x;
  const int tid = threadIdx.x;

  // stage z2[b] -> [t][260], xT[b] -> [e][132]
  {
    const f16x8* zsrc = (const f16x8*)(z2g + (size_t)b * TT * 256);
    for (int c = tid; c < 4096; c += 1024) {
      int t = c >> 5, fc = c & 31;
      f16x8 v = zsrc[c];
      f16x4 lo = __builtin_shufflevector(v, v, 0, 1, 2, 3);
      f16x4 hi = __builtin_shufflevector(v, v, 4, 5, 6, 7);
      _Float16* d = &z2s[t][fc * 8];
      *(f16x4*)d = lo;
      *(f16x4*)(d + 4) = hi;
    }
    const f16x8* xsrc = (const f16x8*)(xTg + (size_t)b * 256 * 128);
    for (int c = tid; c < 4096; c += 1024) {
      int e = c >> 4, tc = c & 15;
      f16x8 v = xsrc[c];
      f16x4 lo = __builtin_shufflevector(v, v, 0, 1, 2, 3);
      f16x4 hi = __builtin_shufflevector(v, v, 4, 5, 6, 7);
      _Float16* d = &xs[e][tc * 8];
      *(f16x4*)d = lo;
      *(f16x4*)(d + 4) = hi;
    }
  }
  if (tid < 256) {
    w3s[tid] = a3w[tid];
    hbuf[tid] = 0.f; cbuf[tid] = 0.f;
    hc8[tid] = (_Float16)0.f; hc8[256 + tid] = (_Float16)0.f;
  }
  if (tid >= 259 && tid < 264) u8[tid] = (_Float16)0.f;
  __syncthreads();  // B0

  const int f_z = tid & 255;
  const int qz = tid >> 8;  // k-quarter for z1 (wave-uniform)
  const _Float16* pa = a1p8 + ((size_t)(qz * 16) * 256 + f_z) * 8;
  const _Float16* pw = whh8 + (size_t)tid * 8;
  const _Float16* pc = wc8 + (size_t)tid * 8;
  const f16x8* hcv = (const f16x8*)hc8;
  const float bc = bcomb[tid];

  // head weights resident in registers
  float whr[8], bh = 0.f;
  if (tid < 192) {
    int o = tid >> 6, lane = tid & 63;
#pragma unroll
    for (int q2 = 0; q2 < 8; ++q2) whr[q2] = whead[o * 512 + lane + (q2 << 6)];
    bh = bhead[o];
  }

  for (int t = 0; t < TT; ++t) {
    float yreg = (tid < 3) ? yg[(size_t)(b * TT + t) * 3 + tid] : 0.f;

    // ---- Phase Z: z1 partials (4-way k-split) + gates_h (n = tid)
    float ghr;
    {
      float za0 = 0.f, za1 = 0.f;
#pragma unroll 4
      for (int i = 0; i < 16; i += 2) {
        f16x8 w0 = *(const f16x8*)(pa + (size_t)i * 2048);
        f16x8 w1 = *(const f16x8*)(pa + (size_t)(i + 1) * 2048);
        f16x8 h0 = hcv[qz * 16 + i];
        f16x8 h1 = hcv[qz * 16 + i + 1];
        za0 = dot8(w0, h0, za0);
        za1 = dot8(w1, h1, za1);
      }
      zpart[tid] = za0 + za1;
      float g0 = 0.f, g1 = 0.f;
#pragma unroll 8
      for (int kc = 0; kc < 32; kc += 2) {
        f16x8 w0 = *(const f16x8*)(pw + (size_t)kc * 8192);
        f16x8 w1 = *(const f16x8*)(pw + (size_t)(kc + 1) * 8192);
        f16x8 h0 = hcv[kc];
        f16x8 h1 = hcv[kc + 1];
        g0 = dot8(w0, h0, g0);
        g1 = dot8(w1, h1, g1);
      }
      ghr = g0 + g1;
    }
    __syncthreads();  // B1

    if (tid < 256)
      z1c[tid] = zpart[tid] + zpart[tid + 256] + zpart[tid + 512] + zpart[tid + 768];
    __syncthreads();  // B2

    // ---- Phase S: scores; tp = tid&127, q = tid>>7 (8 groups x 32 f)
    {
      int tp = tid & 127, q = tid >> 7, f0 = q * 32;
      const _Float16* zr = &z2s[tp][f0];
      float acc = 0.f;
#pragma unroll
      for (int i = 0; i < 8; ++i) {
        f16x4 zz = *(const f16x4*)(zr + i * 4);
#pragma unroll
        for (int j = 0; j < 4; ++j) {
          int f = f0 + i * 4 + j;
          acc = fmaf(tanh_scaled(z1c[f] + (float)zz[j]), w3s[f], acc);
        }
      }
      scpart[tid] = acc;
    }
    __syncthreads();  // B3

    // ---- softmax (no max-sub: |score| <= sum|w3| ~ 25 << 88)
    if (tid < 128) {
      float sc = scpart[tid] + scpart[tid + 128] + scpart[tid + 256] + scpart[tid + 384] +
                 scpart[tid + 512] + scpart[tid + 640] + scpart[tid + 768] + scpart[tid + 896];
      float e = __expf(sc);
      attv[tid] = e;
      float s = e;
#pragma unroll
      for (int off = 32; off > 0; off >>= 1) s += __shfl_xor(s, off);
      if ((tid & 63) == 0) sred[2 + (tid >> 6)] = s;
    }
    __syncthreads();  // B4

    // ---- Phase C: context partials; e = tid&255, th4 = tid>>8 (4 x 32 t)
    {
      int e = tid & 255, th4 = tid >> 8;
      const _Float16* xr = &xs[e][th4 * 32];
      float acc = 0.f;
#pragma unroll
      for (int i = 0; i < 8; ++i) {
        f16x4 xv = *(const f16x4*)(xr + i * 4);
#pragma unroll
        for (int j = 0; j < 4; ++j)
          acc = fmaf(attv[th4 * 32 + i * 4 + j], (float)xv[j], acc);
      }
      cpart[tid] = acc;
    }
    __syncthreads();  // B5

    const float rsum = rcp_fast(sred[2] + sred[3]);
    if (tid < 256) {
      float cv = (cpart[tid] + cpart[tid + 256] + cpart[tid + 512] + cpart[tid + 768]) * rsum;
      ctxs[tid] = cv;
      u8[3 + tid] = (_Float16)cv;
    }
    if (tid < 3) u8[tid] = (_Float16)yreg;
    __syncthreads();  // B6

    // ---- Phase G: gates = W_comb·u + gates_h + b_comb (n = tid)
    {
      float a0 = 0.f, a1 = 0.f;
#pragma unroll 8
      for (int kc = 0; kc < 32; kc += 2) {
        f16x8 w0 = *(const f16x8*)(pc + (size_t)kc * 8192);
        f16x8 w1 = *(const f16x8*)(pc + (size_t)(kc + 1) * 8192);
        f16x8 u0 = *(const f16x8*)&u8[kc * 8];
        f16x8 u1 = *(const f16x8*)&u8[(kc + 1) * 8];
        a0 = dot8(w0, u0, a0);
        a1 = dot8(w1, u1, a1);
      }
      a0 = dot8(*(const f16x8*)(pc + (size_t)32 * 8192), *(const f16x8*)&u8[256], a0);
      gbuf[tid] = a0 + a1 + ghr + bc;
    }
    __syncthreads();  // B7

    // ---- LSTM pointwise
    if (tid < 256) {
      float gi = gbuf[tid], gf = gbuf[tid + 256], gg = gbuf[tid + 512], go = gbuf[tid + 768];
      float cn = fast_sig(gf) * cbuf[tid] + fast_sig(gi) * fast_tanh(gg);
      float hn = fast_sig(go) * fast_tanh(cn);
      if (t < TT - 1) {  // reference skips state update on last step
        hbuf[tid] = hn; cbuf[tid] = cn;
        hc8[tid] = (_Float16)hn; hc8[256 + tid] = (_Float16)cn;
      }
    }
    __syncthreads();  // B8

    // ---- Phase H: out[b,t,o] = W_head[o]·[h2, ctx] + b_head[o]
    if (tid < 192) {
      int o = tid >> 6, lane = tid & 63;
      float acc = 0.f;
#pragma unroll
      for (int q2 = 0; q2 < 8; ++q2) {
        int k = lane + (q2 << 6);
        float v = (k < 256) ? hbuf[k] : ctxs[k - 256];
        acc = fmaf(whr[q2], v, acc);
      }
#pragma unroll
      for (int off = 32; off > 0; off >>= 1) acc += __shfl_xor(acc, off);
      if (lane == 0) outg[(size_t)(b * TT + t) * 3 + o] = acc + bh;
    }
    // no barrier: next phase writes only zpart (disjoint from hbuf/ctxs)
  }
}

// ---------------- launch ----------------

extern "C" void kernel_launch(void* const* d_in, const int* in_sizes, int n_in,
                              void* d_out, int out_size, void* d_ws, size_t ws_size,
                              hipStream_t stream) {
  const float* x   = (const float*)d_in[0];
  const float* y   = (const float*)d_in[1];
  const float* a1w = (const float*)d_in[2];
  const float* a1b = (const float*)d_in[3];
  const float* a2w = (const float*)d_in[4];
  const float* a2b = (const float*)d_in[5];
  const float* a3w = (const float*)d_in[6];
  // d_in[7] = attn3_b: softmax-invariant constant, skipped
  const float* tw  = (const float*)d_in[8];
  const float* tb  = (const float*)d_in[9];
  const float* wih = (const float*)d_in[10];
  const float* whh = (const float*)d_in[11];
  const float* bih = (const float*)d_in[12];
  const float* bhh = (const float*)d_in[13];
  const float* f1w = (const float*)d_in[14];
  const float* f1b = (const float*)d_in[15];
  const float* f2w = (const float*)d_in[16];
  const float* f2b = (const float*)d_in[17];
  float* out = (float*)d_out;

  float* ws = (float*)d_ws;
  _Float16* z2h  = (_Float16*)ws;                       // 8,388,608 h = 4,194,304 f
  _Float16* xT   = (_Float16*)(ws + 4194304);           // 8,388,608 h
  float* a2wT    = ws + 8388608;                        // 65,536 f
  _Float16* a1p8 = (_Float16*)(ws + 8388608 + 65536);   // 131,072 h
  _Float16* whh8 = (_Float16*)(ws + 8388608 + 131072);  // 262,144 h
  _Float16* wc8  = (_Float16*)(ws + 8388608 + 262144);  // 270,336 h
  float* bcomb   = ws + 8388608 + 262144 + 135168;      // 1,024
  float* whead   = bcomb + 1024;                        // 1,536
  float* bhead   = whead + 1536;                        // 3

  k_transpose<<<dim3((256 * 256 + 255) / 256), dim3(256), 0, stream>>>(a2w, a2wT, 256, 256);
  k_z2x<<<dim3(2048), dim3(256), 0, stream>>>(x, a2wT, a2b, a1b, z2h, xT);
  k_pack_a1<<<dim3(512), dim3(256), 0, stream>>>(a1w, a1p8);
  k_pack_whh<<<dim3(1024), dim3(256), 0, stream>>>(whh, whh8);
  k_wcomb<<<dim3(1024), dim3(320), 0, stream>>>(wih, tw, tb, bih, bhh, wc8, bcomb);
  k_whead<<<dim3(1), dim3(512), 0, stream>>>(f1w, f1b, f2w, f2b, whead, bhead);

  k_decoder<<<dim3(256), dim3(1024), 0, stream>>>(z2h, xT, y, a3w, a1p8, whh8, wc8,
                                                  bcomb, whead, bhead, out);
}